// Round 6
// baseline (945.701 us; speedup 1.0000x reference)
//
#include <hip/hip_runtime.h>
#include <hip/hip_bf16.h>

#define TQ 1024
#define TK 8192
#define DH 64
#define NBH 32
#define QT 64      // q rows per block
#define KT 64      // keys per K-tile
#define NW 4       // waves per block
#define ROWS (NBH * TQ)   // 32768 output rows

typedef __attribute__((ext_vector_type(8))) short short8;
typedef __attribute__((ext_vector_type(4))) short short4v;
typedef __attribute__((ext_vector_type(4))) float f32x4;

static __device__ __forceinline__ short f2bf(float f) {
  __hip_bfloat16 h = __float2bfloat16(f);
  return __builtin_bit_cast(short, h);
}

// NS = number of KV chunks; PART: write unnormalized partials + m/l to ws.
template<int NS, bool PART>
__global__ __launch_bounds__(256, 6)
void attn_fwd(const float* __restrict__ qg,
              const float* __restrict__ kg,
              const float* __restrict__ vg,
              const int* __restrict__ qcs_p,
              float* __restrict__ outg,      // PART: opart [NS][NBH][TQ][DH]; else final out
              float* __restrict__ mpart,     // [NS][ROWS] (PART only)
              float* __restrict__ lpart)     // [NS][ROWS] (PART only)
{
  // K tile: [key][d] bf16, elem-swizzle ^((key&7)<<3)  (byte bits 4-6)
  __shared__ __align__(16) short Klds[KT * DH];
  // V tile transposed: [d][key] bf16, elem-swizzle ^(((d>>1)&7)<<3)
  // write: banks spread by d bits 1-3 -> 8-way (was 32-way with d&7)
  // read (b128, d=16ct+li): slot = lg ^ ((li>>1)&7) -> conflict-free
  __shared__ __align__(16) short Vt[DH * KT];
  // per-wave P: [row][key] bf16, elem-swizzle ^((row&7)<<3) (read-optimal)
  __shared__ __align__(16) short Plds[NW][16 * KT];

  const int tid  = threadIdx.x;
  const int wave = tid >> 6;
  const int lane = tid & 63;
  const int lg   = lane >> 4;   // 0..3
  const int li   = lane & 15;   // 0..15

  const int bid = blockIdx.x;
  const int bh  = bid & (NBH - 1);            // low bits -> XCD affinity per head
  const int s   = (bid >> 5) & (NS - 1);      // kv chunk
  const int qt  = bid >> (5 + (NS == 4 ? 2 : 0));
  const int qcs = *qcs_p;

  const int q_base = qt * QT;
  const int wrow   = wave * 16;
  const int chunk_start = s * (TK / NS);
  const int chunk_end   = chunk_start + (TK / NS);

  const float* qp = qg + ((size_t)bh * TQ + q_base + wrow) * DH;
  const float* kp = kg + (size_t)bh * TK * DH;
  const float* vp = vg + (size_t)bh * TK * DH;

  // ---- Q fragments, pre-scaled by 1/sqrt(64) * log2(e) ----
  const float qscale = 0.125f * 1.44269504088896f;
  short8 qf[2];
  #pragma unroll
  for (int h = 0; h < 2; ++h) {
    const float* src = qp + li * DH + h * 32 + lg * 8;
    float4 a = *(const float4*)(src);
    float4 b = *(const float4*)(src + 4);
    short8 f;
    f[0] = f2bf(a.x * qscale); f[1] = f2bf(a.y * qscale);
    f[2] = f2bf(a.z * qscale); f[3] = f2bf(a.w * qscale);
    f[4] = f2bf(b.x * qscale); f[5] = f2bf(b.y * qscale);
    f[6] = f2bf(b.z * qscale); f[7] = f2bf(b.w * qscale);
    qf[h] = f;
  }

  f32x4 o[4];
  #pragma unroll
  for (int ct = 0; ct < 4; ++ct) o[ct] = (f32x4){0.f, 0.f, 0.f, 0.f};
  float rm[4], rl[4];
  #pragma unroll
  for (int r = 0; r < 4; ++r) { rm[r] = -1e30f; rl[r] = 0.f; }

  // block key limit, clamped to this chunk (always > chunk_start here:
  // min limit = 7168+64 > 6144 = max chunk_start for NS=4)
  int lim = qcs + q_base + QT;
  if (lim > chunk_end) lim = chunk_end;
  const int n_tiles = (lim - chunk_start + KT - 1) / KT;

  const int t_key = tid >> 4;        // 0..15
  const int t_d   = (tid & 15) * 4;  // 0..60

  for (int tile = 0; tile < n_tiles; ++tile) {
    const int kt0 = chunk_start + tile * KT;

    // ---- stage K (row-major) and V (transposed), fp32 -> bf16 ----
    #pragma unroll
    for (int it = 0; it < 4; ++it) {
      const int key = t_key + it * 16;
      const size_t goff = (size_t)(kt0 + key) * DH + t_d;
      float4 kv = *(const float4*)(kp + goff);
      short4v ks;
      ks[0] = f2bf(kv.x); ks[1] = f2bf(kv.y);
      ks[2] = f2bf(kv.z); ks[3] = f2bf(kv.w);
      int e = (key * DH + t_d) ^ ((key & 7) << 3);
      *(short4v*)(&Klds[e]) = ks;

      float4 vv = *(const float4*)(vp + goff);
      short vs0 = f2bf(vv.x), vs1 = f2bf(vv.y), vs2 = f2bf(vv.z), vs3 = f2bf(vv.w);
      int d0 = t_d;
      Vt[((d0 + 0) * KT + key) ^ ((((d0 + 0) >> 1) & 7) << 3)] = vs0;
      Vt[((d0 + 1) * KT + key) ^ ((((d0 + 1) >> 1) & 7) << 3)] = vs1;
      Vt[((d0 + 2) * KT + key) ^ ((((d0 + 2) >> 1) & 7) << 3)] = vs2;
      Vt[((d0 + 3) * KT + key) ^ ((((d0 + 3) >> 1) & 7) << 3)] = vs3;
    }
    __syncthreads();

    // ---- S = Q K^T ----
    f32x4 sv[4];
    #pragma unroll
    for (int t = 0; t < 4; ++t) {
      f32x4 acc = (f32x4){0.f, 0.f, 0.f, 0.f};
      #pragma unroll
      for (int h = 0; h < 2; ++h) {
        int e = ((t * 16 + li) * DH + h * 32 + lg * 8) ^ ((li & 7) << 3);
        short8 kf = *(const short8*)(&Klds[e]);
        acc = __builtin_amdgcn_mfma_f32_16x16x32_bf16(qf[h], kf, acc, 0, 0, 0);
      }
      sv[t] = acc;
    }

    // ---- causal mask (boundary tiles only) ----
    if (kt0 + KT - 1 > qcs + q_base + wrow) {
      #pragma unroll
      for (int t = 0; t < 4; ++t) {
        const int keyg = kt0 + t * 16 + li;
        #pragma unroll
        for (int r = 0; r < 4; ++r) {
          const int qpos = qcs + q_base + wrow + lg * 4 + r;
          if (keyg > qpos) sv[t][r] = -INFINITY;
        }
      }
    }

    // ---- online softmax (base-2 domain) ----
    float al[4], mn[4];
    #pragma unroll
    for (int r = 0; r < 4; ++r) {
      float tm = fmaxf(fmaxf(sv[0][r], sv[1][r]), fmaxf(sv[2][r], sv[3][r]));
      #pragma unroll
      for (int off = 1; off < 16; off <<= 1)
        tm = fmaxf(tm, __shfl_xor(tm, off, 64));
      float m2 = fmaxf(rm[r], tm);
      al[r] = __builtin_amdgcn_exp2f(rm[r] - m2);
      mn[r] = m2;
      rm[r] = m2;
    }

    float ps[4] = {0.f, 0.f, 0.f, 0.f};
    #pragma unroll
    for (int t = 0; t < 4; ++t) {
      #pragma unroll
      for (int r = 0; r < 4; ++r) {
        float p = __builtin_amdgcn_exp2f(sv[t][r] - mn[r]);
        ps[r] += p;
        const int row = lg * 4 + r;
        Plds[wave][(row * KT + t * 16 + li) ^ ((row & 7) << 3)] = f2bf(p);
      }
    }

    #pragma unroll
    for (int r = 0; r < 4; ++r) {
      float sum = ps[r];
      #pragma unroll
      for (int off = 1; off < 16; off <<= 1)
        sum += __shfl_xor(sum, off, 64);
      rl[r] = rl[r] * al[r] + sum;
      #pragma unroll
      for (int ct = 0; ct < 4; ++ct) o[ct][r] *= al[r];
    }

    // ---- O += P V ----
    #pragma unroll
    for (int sk = 0; sk < 2; ++sk) {
      int ep = (li * KT + sk * 32 + lg * 8) ^ ((li & 7) << 3);
      short8 pf = *(const short8*)(&Plds[wave][ep]);
      #pragma unroll
      for (int ct = 0; ct < 4; ++ct) {
        int d = ct * 16 + li;
        int ev = (d * KT + sk * 32 + lg * 8) ^ (((d >> 1) & 7) << 3);
        short8 vf = *(const short8*)(&Vt[ev]);
        o[ct] = __builtin_amdgcn_mfma_f32_16x16x32_bf16(pf, vf, o[ct], 0, 0, 0);
      }
    }
    __syncthreads();
  }

  // ---- epilogue ----
  if constexpr (PART) {
    float* opr = outg + (((size_t)s * NBH + bh) * TQ + q_base + wrow) * DH;
    const size_t rbase = ((size_t)s * NBH + bh) * TQ + q_base + wrow;
    #pragma unroll
    for (int r = 0; r < 4; ++r) {
      #pragma unroll
      for (int ct = 0; ct < 4; ++ct)
        opr[(lg * 4 + r) * DH + ct * 16 + li] = o[ct][r];   // unnormalized
      if (li == 0) {
        mpart[rbase + lg * 4 + r] = rm[r];
        lpart[rbase + lg * 4 + r] = rl[r];
      }
    }
  } else {
    float* op = outg + ((size_t)bh * TQ + q_base + wrow) * DH;
    #pragma unroll
    for (int r = 0; r < 4; ++r) {
      const float inv = rl[r] > 0.f ? 1.0f / rl[r] : 0.f;
      #pragma unroll
      for (int ct = 0; ct < 4; ++ct)
        op[(lg * 4 + r) * DH + ct * 16 + li] = o[ct][r] * inv;
    }
  }
}

template<int NS>
__global__ __launch_bounds__(256)
void combine(const float* __restrict__ opart,
             const float* __restrict__ mp,
             const float* __restrict__ lp,
             float* __restrict__ outg)
{
  const int gid = blockIdx.x * 256 + threadIdx.x;
  const int rg = gid >> 6;     // global row 0..ROWS-1
  const int d  = gid & 63;

  float m[NS], l[NS];
  float M = -1e30f;
  #pragma unroll
  for (int s = 0; s < NS; ++s) {
    m[s] = mp[(size_t)s * ROWS + rg];
    l[s] = lp[(size_t)s * ROWS + rg];
    M = fmaxf(M, m[s]);
  }
  float L = 0.f, acc = 0.f;
  #pragma unroll
  for (int s = 0; s < NS; ++s) {
    float w = __builtin_amdgcn_exp2f(m[s] - M);
    L += w * l[s];
    acc += w * opart[((size_t)s * ROWS + rg) * DH + d];
  }
  outg[(size_t)rg * DH + d] = L > 0.f ? acc / L : 0.f;
}

extern "C" void kernel_launch(void* const* d_in, const int* in_sizes, int n_in,
                              void* d_out, int out_size, void* d_ws, size_t ws_size,
                              hipStream_t stream) {
  const float* q   = (const float*)d_in[0];
  const float* k   = (const float*)d_in[1];
  const float* v   = (const float*)d_in[2];
  const int*   qcs = (const int*)d_in[3];
  float* out = (float*)d_out;

  constexpr int    NS = 4;
  constexpr size_t O_ELEMS  = (size_t)NS * ROWS * DH;       // partial O
  constexpr size_t ML_ELEMS = (size_t)NS * ROWS;            // m and l each
  constexpr size_t WS_NEED  = (O_ELEMS + 2 * ML_ELEMS) * sizeof(float);

  if (ws_size >= WS_NEED) {
    float* opart = (float*)d_ws;
    float* mpart = opart + O_ELEMS;
    float* lpart = mpart + ML_ELEMS;
    dim3 grid(NBH * NS * (TQ / QT));   // 2048 blocks: bits [0:4]=bh [5:6]=s [7:]=qt
    attn_fwd<NS, true><<<grid, dim3(256), 0, stream>>>(q, k, v, qcs, opart, mpart, lpart);
    combine<NS><<<dim3(ROWS * DH / 256), dim3(256), 0, stream>>>(opart, mpart, lpart, out);
  } else {
    dim3 grid(NBH * (TQ / QT));        // fallback: single-pass, 512 blocks
    attn_fwd<1, false><<<grid, dim3(256), 0, stream>>>(q, k, v, qcs, out, nullptr, nullptr);
  }
}

// Round 9
// 382.975 us; speedup vs baseline: 2.4694x; 2.4694x over previous
//
#include <hip/hip_runtime.h>
#include <hip/hip_bf16.h>

#define TQ 1024
#define TK 8192
#define DH 64
#define NBH 32
#define QT 64      // q rows per block
#define KT 64      // keys per K-tile
#define NW 4       // waves per block
#define NTILE (TK / KT)          // 128 key-tiles per head
#define TILE_E (KT * DH)         // 4096 elems per tile image

typedef __attribute__((ext_vector_type(8))) short short8;
typedef __attribute__((ext_vector_type(4))) short short4v;
typedef __attribute__((ext_vector_type(4))) float f32x4;

static __device__ __forceinline__ short f2bf(float f) {
  __hip_bfloat16 h = __float2bfloat16(f);
  return __builtin_bit_cast(short, h);
}

// global_load_lds: 16B per lane; LDS dest = uniform base + lane*16 (HW rule)
#define GLD16(gsrc, ldst)                                                     \
  __builtin_amdgcn_global_load_lds(                                           \
      (const __attribute__((address_space(1))) unsigned int*)(gsrc),          \
      (__attribute__((address_space(3))) unsigned int*)(ldst), 16, 0, 0)

// ---------------- pre-pass: fp32 K/V -> bf16 pre-swizzled tile images -------
// Kimg tile: elem (key*64+d) ^ ((key&7)<<3)   (K fragment reads conflict-free)
// Vimg tile: elem (d*64+key) ^ ((d&7)<<3)     (transposed; PV B-frag reads free)
__global__ __launch_bounds__(256)
void prep(const float* __restrict__ kg, const float* __restrict__ vg,
          short* __restrict__ Kg2, short* __restrict__ Vg2)
{
  __shared__ __align__(16) short Ki[TILE_E];
  __shared__ __align__(16) short Vi[TILE_E];
  const int bid = blockIdx.x;            // [head][tile]
  const int h = bid >> 7, t = bid & (NTILE - 1);
  const int tid = threadIdx.x;
  const int t_key = tid >> 4;            // 0..15
  const int t_d   = (tid & 15) * 4;      // 0..60

  const float* kp = kg + ((size_t)h * TK + (size_t)t * KT) * DH;
  const float* vp = vg + ((size_t)h * TK + (size_t)t * KT) * DH;

  #pragma unroll
  for (int it = 0; it < 4; ++it) {
    const int key = t_key + it * 16;
    float4 kv = *(const float4*)(kp + key * DH + t_d);
    short4v ks;
    ks[0] = f2bf(kv.x); ks[1] = f2bf(kv.y); ks[2] = f2bf(kv.z); ks[3] = f2bf(kv.w);
    *(short4v*)(&Ki[(key * 64 + t_d) ^ ((key & 7) << 3)]) = ks;

    float4 vv = *(const float4*)(vp + key * DH + t_d);
    Vi[((t_d + 0) * 64 + key) ^ (((t_d + 0) & 7) << 3)] = f2bf(vv.x);
    Vi[((t_d + 1) * 64 + key) ^ (((t_d + 1) & 7) << 3)] = f2bf(vv.y);
    Vi[((t_d + 2) * 64 + key) ^ (((t_d + 2) & 7) << 3)] = f2bf(vv.z);
    Vi[((t_d + 3) * 64 + key) ^ (((t_d + 3) & 7) << 3)] = f2bf(vv.w);
  }
  __syncthreads();

  const size_t base = (size_t)bid * TILE_E;
  *(short8*)(&Kg2[base + tid * 16])     = *(short8*)(&Ki[tid * 16]);
  *(short8*)(&Kg2[base + tid * 16 + 8]) = *(short8*)(&Ki[tid * 16 + 8]);
  *(short8*)(&Vg2[base + tid * 16])     = *(short8*)(&Vi[tid * 16]);
  *(short8*)(&Vg2[base + tid * 16 + 8]) = *(short8*)(&Vi[tid * 16 + 8]);
}

// ---------------- main: double-buffered global_load_lds flash attention -----
__global__ __launch_bounds__(256, 2)
void attn_main(const float* __restrict__ qg,
               const short* __restrict__ Kg2,
               const short* __restrict__ Vg2,
               const int* __restrict__ qcs_p,
               float* __restrict__ outg)
{
  __shared__ __align__(16) short Kb[2][TILE_E];
  __shared__ __align__(16) short Vb[2][TILE_E];
  __shared__ __align__(16) short Plds[NW][16 * KT];

  const int tid  = threadIdx.x;
  const int wave = tid >> 6;
  const int lane = tid & 63;
  const int lg   = lane >> 4;
  const int li   = lane & 15;

  const int bid = blockIdx.x;
  const int bh  = bid & (NBH - 1);   // same-head blocks share XCD
  const int qt  = bid >> 5;
  const int qcs = *qcs_p;

  const int q_base = qt * QT;
  const int wrow   = wave * 16;

  const float* qp = qg + ((size_t)bh * TQ + q_base + wrow) * DH;
  const size_t tile_base0 = (size_t)bh * NTILE * TILE_E;

  // ---- Q fragments, pre-scaled by 1/sqrt(64) * log2(e) ----
  const float qscale = 0.125f * 1.44269504088896f;
  short8 qf[2];
  #pragma unroll
  for (int h = 0; h < 2; ++h) {
    const float* src = qp + li * DH + h * 32 + lg * 8;
    float4 a = *(const float4*)(src);
    float4 b = *(const float4*)(src + 4);
    short8 f;
    f[0] = f2bf(a.x * qscale); f[1] = f2bf(a.y * qscale);
    f[2] = f2bf(a.z * qscale); f[3] = f2bf(a.w * qscale);
    f[4] = f2bf(b.x * qscale); f[5] = f2bf(b.y * qscale);
    f[6] = f2bf(b.z * qscale); f[7] = f2bf(b.w * qscale);
    qf[h] = f;
  }

  f32x4 o[4];
  #pragma unroll
  for (int ct = 0; ct < 4; ++ct) o[ct] = (f32x4){0.f, 0.f, 0.f, 0.f};
  float rm[4], rl[4];
  #pragma unroll
  for (int r = 0; r < 4; ++r) { rm[r] = -1e30f; rl[r] = 0.f; }

  const int lim    = qcs + q_base + QT;
  const int n_keys = lim < TK ? lim : TK;
  const int n_tiles = (n_keys + KT - 1) / KT;

  const int chunk = wave * 2;          // 2 chunks of 1024B per wave, x4 waves = 8KB

  // stage tile -> buffer b (4x global_load_lds per thread-wave slot)
  auto stage = [&](int b, int tile) {
    const size_t tb = tile_base0 + (size_t)tile * TILE_E;
    GLD16(Kg2 + tb + (chunk + 0) * 512 + lane * 8, &Kb[b][(chunk + 0) * 512]);
    GLD16(Kg2 + tb + (chunk + 1) * 512 + lane * 8, &Kb[b][(chunk + 1) * 512]);
    GLD16(Vg2 + tb + (chunk + 0) * 512 + lane * 8, &Vb[b][(chunk + 0) * 512]);
    GLD16(Vg2 + tb + (chunk + 1) * 512 + lane * 8, &Vb[b][(chunk + 1) * 512]);
  };

  stage(0, 0);
  __syncthreads();                     // drains vmcnt -> buf0 ready
  int buf = 0;

  for (int tile = 0; tile < n_tiles; ++tile) {
    const int kt0 = tile * KT;
    if (tile + 1 < n_tiles) stage(buf ^ 1, tile + 1);   // in flight during compute

    // ---- S = Q K^T ----
    f32x4 sv[4];
    __builtin_amdgcn_s_setprio(1);
    #pragma unroll
    for (int t = 0; t < 4; ++t) {
      f32x4 acc = (f32x4){0.f, 0.f, 0.f, 0.f};
      #pragma unroll
      for (int h = 0; h < 2; ++h) {
        int e = ((t * 16 + li) * 64 + h * 32 + lg * 8) ^ ((li & 7) << 3);
        short8 kf = *(const short8*)(&Kb[buf][e]);
        acc = __builtin_amdgcn_mfma_f32_16x16x32_bf16(qf[h], kf, acc, 0, 0, 0);
      }
      sv[t] = acc;
    }
    __builtin_amdgcn_s_setprio(0);

    // ---- causal mask (boundary tiles only) ----
    if (kt0 + KT - 1 > qcs + q_base + wrow) {
      #pragma unroll
      for (int t = 0; t < 4; ++t) {
        const int keyg = kt0 + t * 16 + li;
        #pragma unroll
        for (int r = 0; r < 4; ++r) {
          const int qpos = qcs + q_base + wrow + lg * 4 + r;
          if (keyg > qpos) sv[t][r] = -INFINITY;
        }
      }
    }

    // ---- online softmax (base-2 domain) ----
    float al[4], mn[4];
    #pragma unroll
    for (int r = 0; r < 4; ++r) {
      float tm = fmaxf(fmaxf(sv[0][r], sv[1][r]), fmaxf(sv[2][r], sv[3][r]));
      #pragma unroll
      for (int off = 1; off < 16; off <<= 1)
        tm = fmaxf(tm, __shfl_xor(tm, off, 64));
      float m2 = fmaxf(rm[r], tm);
      al[r] = __builtin_amdgcn_exp2f(rm[r] - m2);
      mn[r] = m2;
      rm[r] = m2;
    }

    float ps[4] = {0.f, 0.f, 0.f, 0.f};
    #pragma unroll
    for (int t = 0; t < 4; ++t) {
      #pragma unroll
      for (int r = 0; r < 4; ++r) {
        float p = __builtin_amdgcn_exp2f(sv[t][r] - mn[r]);
        ps[r] += p;
        const int row = lg * 4 + r;
        Plds[wave][(row * KT + t * 16 + li) ^ ((row & 7) << 3)] = f2bf(p);
      }
    }

    #pragma unroll
    for (int r = 0; r < 4; ++r) {
      float sum = ps[r];
      #pragma unroll
      for (int off = 1; off < 16; off <<= 1)
        sum += __shfl_xor(sum, off, 64);
      rl[r] = rl[r] * al[r] + sum;
      #pragma unroll
      for (int ct = 0; ct < 4; ++ct) o[ct][r] *= al[r];
    }

    // ---- O += P V ----
    #pragma unroll
    for (int sk = 0; sk < 2; ++sk) {
      int ep = (li * KT + sk * 32 + lg * 8) ^ ((li & 7) << 3);
      short8 pf = *(const short8*)(&Plds[wave][ep]);
      __builtin_amdgcn_s_setprio(1);
      #pragma unroll
      for (int ct = 0; ct < 4; ++ct) {
        int e = ((ct * 16 + li) * 64 + sk * 32 + lg * 8) ^ ((li & 7) << 3);
        short8 vf = *(const short8*)(&Vb[buf][e]);
        o[ct] = __builtin_amdgcn_mfma_f32_16x16x32_bf16(pf, vf, o[ct], 0, 0, 0);
      }
      __builtin_amdgcn_s_setprio(0);
    }

    __syncthreads();   // drains stage loads (vmcnt0) + protects buf reuse
    buf ^= 1;
  }

  // ---- epilogue ----
  float* op = outg + ((size_t)bh * TQ + q_base + wrow) * DH;
  #pragma unroll
  for (int r = 0; r < 4; ++r) {
    const float inv = rl[r] > 0.f ? 1.0f / rl[r] : 0.f;
    #pragma unroll
    for (int ct = 0; ct < 4; ++ct)
      op[(lg * 4 + r) * DH + ct * 16 + li] = o[ct][r] * inv;
  }
}

// ---------------- fallback: self-staging single pass (round-5 proven) -------
__global__ __launch_bounds__(256, 2)
void attn_fallback(const float* __restrict__ qg,
                   const float* __restrict__ kg,
                   const float* __restrict__ vg,
                   const int* __restrict__ qcs_p,
                   float* __restrict__ outg)
{
  __shared__ __align__(16) short Klds[KT * DH];
  __shared__ __align__(16) short Vt[DH * KT];
  __shared__ __align__(16) short Plds[NW][16 * KT];

  const int tid  = threadIdx.x;
  const int wave = tid >> 6;
  const int lane = tid & 63;
  const int lg   = lane >> 4;
  const int li   = lane & 15;

  const int bid = blockIdx.x;
  const int bh  = bid & (NBH - 1);
  const int qt  = bid >> 5;
  const int qcs = *qcs_p;

  const int q_base = qt * QT;
  const int wrow   = wave * 16;

  const float* qp = qg + ((size_t)bh * TQ + q_base + wrow) * DH;
  const float* kp = kg + (size_t)bh * TK * DH;
  const float* vp = vg + (size_t)bh * TK * DH;

  const float qscale = 0.125f * 1.44269504088896f;
  short8 qf[2];
  #pragma unroll
  for (int h = 0; h < 2; ++h) {
    const float* src = qp + li * DH + h * 32 + lg * 8;
    float4 a = *(const float4*)(src);
    float4 b = *(const float4*)(src + 4);
    short8 f;
    f[0] = f2bf(a.x * qscale); f[1] = f2bf(a.y * qscale);
    f[2] = f2bf(a.z * qscale); f[3] = f2bf(a.w * qscale);
    f[4] = f2bf(b.x * qscale); f[5] = f2bf(b.y * qscale);
    f[6] = f2bf(b.z * qscale); f[7] = f2bf(b.w * qscale);
    qf[h] = f;
  }

  f32x4 o[4];
  #pragma unroll
  for (int ct = 0; ct < 4; ++ct) o[ct] = (f32x4){0.f, 0.f, 0.f, 0.f};
  float rm[4], rl[4];
  #pragma unroll
  for (int r = 0; r < 4; ++r) { rm[r] = -1e30f; rl[r] = 0.f; }

  const int lim    = qcs + q_base + QT;
  const int n_keys = lim < TK ? lim : TK;
  const int n_tiles = (n_keys + KT - 1) / KT;

  const int t_key = tid >> 4;
  const int t_d   = (tid & 15) * 4;

  for (int tile = 0; tile < n_tiles; ++tile) {
    const int kt0 = tile * KT;
    #pragma unroll
    for (int it = 0; it < 4; ++it) {
      const int key = t_key + it * 16;
      const size_t goff = (size_t)(kt0 + key) * DH + t_d;
      float4 kv = *(const float4*)(kp + goff);
      short4v ks;
      ks[0] = f2bf(kv.x); ks[1] = f2bf(kv.y); ks[2] = f2bf(kv.z); ks[3] = f2bf(kv.w);
      *(short4v*)(&Klds[(key * DH + t_d) ^ ((key & 7) << 3)]) = ks;

      float4 vv = *(const float4*)(vp + goff);
      Vt[((t_d + 0) * KT + key) ^ ((((t_d + 0) >> 1) & 7) << 3)] = f2bf(vv.x);
      Vt[((t_d + 1) * KT + key) ^ ((((t_d + 1) >> 1) & 7) << 3)] = f2bf(vv.y);
      Vt[((t_d + 2) * KT + key) ^ ((((t_d + 2) >> 1) & 7) << 3)] = f2bf(vv.z);
      Vt[((t_d + 3) * KT + key) ^ ((((t_d + 3) >> 1) & 7) << 3)] = f2bf(vv.w);
    }
    __syncthreads();

    f32x4 sv[4];
    #pragma unroll
    for (int t = 0; t < 4; ++t) {
      f32x4 acc = (f32x4){0.f, 0.f, 0.f, 0.f};
      #pragma unroll
      for (int h = 0; h < 2; ++h) {
        int e = ((t * 16 + li) * DH + h * 32 + lg * 8) ^ ((li & 7) << 3);
        short8 kf = *(const short8*)(&Klds[e]);
        acc = __builtin_amdgcn_mfma_f32_16x16x32_bf16(qf[h], kf, acc, 0, 0, 0);
      }
      sv[t] = acc;
    }

    if (kt0 + KT - 1 > qcs + q_base + wrow) {
      #pragma unroll
      for (int t = 0; t < 4; ++t) {
        const int keyg = kt0 + t * 16 + li;
        #pragma unroll
        for (int r = 0; r < 4; ++r) {
          const int qpos = qcs + q_base + wrow + lg * 4 + r;
          if (keyg > qpos) sv[t][r] = -INFINITY;
        }
      }
    }

    float al[4], mn[4];
    #pragma unroll
    for (int r = 0; r < 4; ++r) {
      float tm = fmaxf(fmaxf(sv[0][r], sv[1][r]), fmaxf(sv[2][r], sv[3][r]));
      #pragma unroll
      for (int off = 1; off < 16; off <<= 1)
        tm = fmaxf(tm, __shfl_xor(tm, off, 64));
      float m2 = fmaxf(rm[r], tm);
      al[r] = __builtin_amdgcn_exp2f(rm[r] - m2);
      mn[r] = m2;
      rm[r] = m2;
    }

    float ps[4] = {0.f, 0.f, 0.f, 0.f};
    #pragma unroll
    for (int t = 0; t < 4; ++t) {
      #pragma unroll
      for (int r = 0; r < 4; ++r) {
        float p = __builtin_amdgcn_exp2f(sv[t][r] - mn[r]);
        ps[r] += p;
        const int row = lg * 4 + r;
        Plds[wave][(row * KT + t * 16 + li) ^ ((row & 7) << 3)] = f2bf(p);
      }
    }

    #pragma unroll
    for (int r = 0; r < 4; ++r) {
      float sum = ps[r];
      #pragma unroll
      for (int off = 1; off < 16; off <<= 1)
        sum += __shfl_xor(sum, off, 64);
      rl[r] = rl[r] * al[r] + sum;
      #pragma unroll
      for (int ct = 0; ct < 4; ++ct) o[ct][r] *= al[r];
    }

    #pragma unroll
    for (int sk = 0; sk < 2; ++sk) {
      int ep = (li * KT + sk * 32 + lg * 8) ^ ((li & 7) << 3);
      short8 pf = *(const short8*)(&Plds[wave][ep]);
      #pragma unroll
      for (int ct = 0; ct < 4; ++ct) {
        int d = ct * 16 + li;
        int ev = (d * KT + sk * 32 + lg * 8) ^ (((d >> 1) & 7) << 3);
        short8 vf = *(const short8*)(&Vt[ev]);
        o[ct] = __builtin_amdgcn_mfma_f32_16x16x32_bf16(pf, vf, o[ct], 0, 0, 0);
      }
    }
    __syncthreads();
  }

  float* op = outg + ((size_t)bh * TQ + q_base + wrow) * DH;
  #pragma unroll
  for (int r = 0; r < 4; ++r) {
    const float inv = rl[r] > 0.f ? 1.0f / rl[r] : 0.f;
    #pragma unroll
    for (int ct = 0; ct < 4; ++ct)
      op[(lg * 4 + r) * DH + ct * 16 + li] = o[ct][r] * inv;
  }
}

extern "C" void kernel_launch(void* const* d_in, const int* in_sizes, int n_in,
                              void* d_out, int out_size, void* d_ws, size_t ws_size,
                              hipStream_t stream) {
  const float* q   = (const float*)d_in[0];
  const float* k   = (const float*)d_in[1];
  const float* v   = (const float*)d_in[2];
  const int*   qcs = (const int*)d_in[3];
  float* out = (float*)d_out;

  constexpr size_t IMG_ELEMS = (size_t)NBH * NTILE * TILE_E;       // 16.8M shorts
  constexpr size_t WS_NEED   = 2 * IMG_ELEMS * sizeof(short);      // 64 MB

  if (ws_size >= WS_NEED) {
    short* Kg2 = (short*)d_ws;
    short* Vg2 = Kg2 + IMG_ELEMS;
    prep<<<dim3(NBH * NTILE), dim3(256), 0, stream>>>(k, v, Kg2, Vg2);
    attn_main<<<dim3(NBH * (TQ / QT)), dim3(256), 0, stream>>>(q, Kg2, Vg2, qcs, out);
  } else {
    attn_fallback<<<dim3(NBH * (TQ / QT)), dim3(256), 0, stream>>>(q, k, v, qcs, out);
  }
}

// Round 14
// 363.317 us; speedup vs baseline: 2.6030x; 1.0541x over previous
//
#include <hip/hip_runtime.h>
#include <hip/hip_bf16.h>

#define TQ 1024
#define TK 8192
#define DH 64
#define NBH 32
#define QT 64      // q rows per block
#define KT 64      // keys per K-tile
#define NW 4       // waves per block
#define NTILE (TK / KT)          // 128 key-tiles per head
#define TILE_E (KT * DH)         // 4096 elems per tile image
#define ROWS (NBH * TQ)          // 32768 output rows

typedef __attribute__((ext_vector_type(8))) short short8;
typedef __attribute__((ext_vector_type(4))) short short4v;
typedef __attribute__((ext_vector_type(4))) float f32x4;

static __device__ __forceinline__ short f2bf(float f) {
  __hip_bfloat16 h = __float2bfloat16(f);
  return __builtin_bit_cast(short, h);
}

// global_load_lds: 16B per lane; LDS dest = uniform base + lane*16 (HW rule)
#define GLD16(gsrc, ldst)                                                     \
  __builtin_amdgcn_global_load_lds(                                           \
      (const __attribute__((address_space(1))) unsigned int*)(gsrc),          \
      (__attribute__((address_space(3))) unsigned int*)(ldst), 16, 0, 0)

// ---------------- pre-pass: fp32 K/V -> bf16 pre-swizzled tile images -------
// No LDS: K rows written permuted-in-row (coalesced); V transposed 4x4 in
// registers, 8B global writes merged by L2.
// Kimg tile: elem (key*64+d) ^ ((key&7)<<3)
// Vimg tile: elem (d*64+key) ^ ((d&7)<<3)
__global__ __launch_bounds__(256)
void prep(const float* __restrict__ kg, const float* __restrict__ vg,
          short* __restrict__ Kg2, short* __restrict__ Vg2)
{
  const int bid = blockIdx.x;            // [head][tile]
  const int h = bid >> 7, t = bid & (NTILE - 1);
  const int tid = threadIdx.x;
  const int kq = tid >> 4;               // key-quad 0..15
  const int dq = tid & 15;               // d-quad   0..15

  const float* kp = kg + ((size_t)h * TK + (size_t)t * KT) * DH;
  const float* vp = vg + ((size_t)h * TK + (size_t)t * KT) * DH;
  const size_t base = (size_t)bid * TILE_E;

  #pragma unroll
  for (int j = 0; j < 4; ++j) {
    const int key = 4 * kq + j;
    float4 kv = *(const float4*)(kp + key * DH + 4 * dq);
    short4v ks;
    ks[0] = f2bf(kv.x); ks[1] = f2bf(kv.y); ks[2] = f2bf(kv.z); ks[3] = f2bf(kv.w);
    *(short4v*)(&Kg2[base + ((key * 64 + 4 * dq) ^ ((key & 7) << 3))]) = ks;
  }

  float4 v0 = *(const float4*)(vp + (4 * kq + 0) * DH + 4 * dq);
  float4 v1 = *(const float4*)(vp + (4 * kq + 1) * DH + 4 * dq);
  float4 v2 = *(const float4*)(vp + (4 * kq + 2) * DH + 4 * dq);
  float4 v3 = *(const float4*)(vp + (4 * kq + 3) * DH + 4 * dq);
  #pragma unroll
  for (int i = 0; i < 4; ++i) {
    const int d = 4 * dq + i;
    short4v vs;
    vs[0] = f2bf(((const float*)&v0)[i]);
    vs[1] = f2bf(((const float*)&v1)[i]);
    vs[2] = f2bf(((const float*)&v2)[i]);
    vs[3] = f2bf(((const float*)&v3)[i]);
    *(short4v*)(&Vg2[base + ((d * 64 + 4 * kq) ^ ((d & 7) << 3))]) = vs;
  }
}

// ---------------- main: double-buffered global_load_lds flash attention -----
// NS=2: 2-way KV split, 1024 blocks = exactly 4/CU co-resident.
template<int NS, bool PART>
__global__ __launch_bounds__(256, (NS == 2 ? 4 : 2))
void attn_main(const float* __restrict__ qg,
               const short* __restrict__ Kg2,
               const short* __restrict__ Vg2,
               const int* __restrict__ qcs_p,
               float* __restrict__ outg,      // PART: opart [NS][NBH][TQ][DH]
               float* __restrict__ mpart,     // [NS][ROWS]
               float* __restrict__ lpart)     // [NS][ROWS]
{
  __shared__ __align__(16) short Kb[2][TILE_E];
  __shared__ __align__(16) short Vb[2][TILE_E];
  __shared__ __align__(16) short Plds[NW][16 * KT];

  const int tid  = threadIdx.x;
  const int wave = tid >> 6;
  const int lane = tid & 63;
  const int lg   = lane >> 4;
  const int li   = lane & 15;

  const int bid = blockIdx.x;
  const int bh  = bid & (NBH - 1);             // bid%8 == bh%8 -> per-head XCD
  const int s   = (bid >> 5) & (NS - 1);
  const int qt  = bid >> (NS == 2 ? 6 : 5);
  const int qcs = *qcs_p;

  const int q_base = qt * QT;
  const int wrow   = wave * 16;
  const int chunk_start = s * (TK / NS);

  const float* qp = qg + ((size_t)bh * TQ + q_base + wrow) * DH;
  const size_t tile_base0 = (size_t)bh * NTILE * TILE_E;
  const int gt0 = chunk_start / KT;

  // ---- Q fragments, pre-scaled by 1/sqrt(64) * log2(e) ----
  const float qscale = 0.125f * 1.44269504088896f;
  short8 qf[2];
  #pragma unroll
  for (int h = 0; h < 2; ++h) {
    const float* src = qp + li * DH + h * 32 + lg * 8;
    float4 a = *(const float4*)(src);
    float4 b = *(const float4*)(src + 4);
    short8 f;
    f[0] = f2bf(a.x * qscale); f[1] = f2bf(a.y * qscale);
    f[2] = f2bf(a.z * qscale); f[3] = f2bf(a.w * qscale);
    f[4] = f2bf(b.x * qscale); f[5] = f2bf(b.y * qscale);
    f[6] = f2bf(b.z * qscale); f[7] = f2bf(b.w * qscale);
    qf[h] = f;
  }

  f32x4 o[4];
  #pragma unroll
  for (int ct = 0; ct < 4; ++ct) o[ct] = (f32x4){0.f, 0.f, 0.f, 0.f};
  float rm[4], rl[4];
  #pragma unroll
  for (int r = 0; r < 4; ++r) { rm[r] = -1e30f; rl[r] = 0.f; }

  // key limit clamped to this chunk; qcs=7168 > max chunk_start -> n_tiles >= 1
  int lim = qcs + q_base + QT;
  if (lim > TK) lim = TK;
  if (lim > chunk_start + TK / NS) lim = chunk_start + TK / NS;
  const int n_tiles = (lim - chunk_start + KT - 1) / KT;

  const int chunk = wave * 2;          // 2x 1KB LDS chunks per wave

  auto stage = [&](int b, int lt) {
    const size_t tb = tile_base0 + (size_t)(gt0 + lt) * TILE_E;
    GLD16(Kg2 + tb + (chunk + 0) * 512 + lane * 8, &Kb[b][(chunk + 0) * 512]);
    GLD16(Kg2 + tb + (chunk + 1) * 512 + lane * 8, &Kb[b][(chunk + 1) * 512]);
    GLD16(Vg2 + tb + (chunk + 0) * 512 + lane * 8, &Vb[b][(chunk + 0) * 512]);
    GLD16(Vg2 + tb + (chunk + 1) * 512 + lane * 8, &Vb[b][(chunk + 1) * 512]);
  };

  stage(0, 0);
  __syncthreads();
  int buf = 0;

  for (int lt = 0; lt < n_tiles; ++lt) {
    const int kt0 = chunk_start + lt * KT;
    if (lt + 1 < n_tiles) stage(buf ^ 1, lt + 1);

    // ---- S = Q K^T ----
    f32x4 sv[4];
    __builtin_amdgcn_s_setprio(1);
    #pragma unroll
    for (int t = 0; t < 4; ++t) {
      f32x4 acc = (f32x4){0.f, 0.f, 0.f, 0.f};
      #pragma unroll
      for (int h = 0; h < 2; ++h) {
        int e = ((t * 16 + li) * 64 + h * 32 + lg * 8) ^ ((li & 7) << 3);
        short8 kf = *(const short8*)(&Kb[buf][e]);
        acc = __builtin_amdgcn_mfma_f32_16x16x32_bf16(qf[h], kf, acc, 0, 0, 0);
      }
      sv[t] = acc;
    }
    __builtin_amdgcn_s_setprio(0);

    // ---- causal mask (only chunk-boundary tiles can trigger) ----
    if (kt0 + KT - 1 > qcs + q_base + wrow) {
      #pragma unroll
      for (int t = 0; t < 4; ++t) {
        const int keyg = kt0 + t * 16 + li;
        #pragma unroll
        for (int r = 0; r < 4; ++r) {
          const int qpos = qcs + q_base + wrow + lg * 4 + r;
          if (keyg > qpos) sv[t][r] = -INFINITY;
        }
      }
    }

    // ---- online softmax (base-2 domain) ----
    float al[4], mn[4];
    #pragma unroll
    for (int r = 0; r < 4; ++r) {
      float tm = fmaxf(fmaxf(sv[0][r], sv[1][r]), fmaxf(sv[2][r], sv[3][r]));
      #pragma unroll
      for (int off = 1; off < 16; off <<= 1)
        tm = fmaxf(tm, __shfl_xor(tm, off, 64));
      float m2 = fmaxf(rm[r], tm);
      al[r] = __builtin_amdgcn_exp2f(rm[r] - m2);
      mn[r] = m2;
      rm[r] = m2;
    }

    float ps[4] = {0.f, 0.f, 0.f, 0.f};
    #pragma unroll
    for (int t = 0; t < 4; ++t) {
      #pragma unroll
      for (int r = 0; r < 4; ++r) {
        float p = __builtin_amdgcn_exp2f(sv[t][r] - mn[r]);
        ps[r] += p;
        const int row = lg * 4 + r;
        Plds[wave][(row * KT + t * 16 + li) ^ ((row & 7) << 3)] = f2bf(p);
      }
    }

    #pragma unroll
    for (int r = 0; r < 4; ++r) {
      float sum = ps[r];
      #pragma unroll
      for (int off = 1; off < 16; off <<= 1)
        sum += __shfl_xor(sum, off, 64);
      rl[r] = rl[r] * al[r] + sum;
      #pragma unroll
      for (int ct = 0; ct < 4; ++ct) o[ct][r] *= al[r];
    }

    // ---- O += P V ----
    #pragma unroll
    for (int sk = 0; sk < 2; ++sk) {
      int ep = (li * KT + sk * 32 + lg * 8) ^ ((li & 7) << 3);
      short8 pf = *(const short8*)(&Plds[wave][ep]);
      __builtin_amdgcn_s_setprio(1);
      #pragma unroll
      for (int ct = 0; ct < 4; ++ct) {
        int e = ((ct * 16 + li) * 64 + sk * 32 + lg * 8) ^ ((li & 7) << 3);
        short8 vf = *(const short8*)(&Vb[buf][e]);
        o[ct] = __builtin_amdgcn_mfma_f32_16x16x32_bf16(pf, vf, o[ct], 0, 0, 0);
      }
      __builtin_amdgcn_s_setprio(0);
    }

    __syncthreads();   // drains stage loads + protects buf reuse
    buf ^= 1;
  }

  // ---- epilogue ----
  if constexpr (PART) {
    const size_t rbase = ((size_t)s * NBH + bh) * TQ + q_base + wrow;
    float* opr = outg + rbase * DH;
    #pragma unroll
    for (int r = 0; r < 4; ++r) {
      #pragma unroll
      for (int ct = 0; ct < 4; ++ct)
        opr[(lg * 4 + r) * DH + ct * 16 + li] = o[ct][r];   // unnormalized
      if (li == 0) {
        mpart[rbase + lg * 4 + r] = rm[r];
        lpart[rbase + lg * 4 + r] = rl[r];
      }
    }
  } else {
    float* op = outg + ((size_t)bh * TQ + q_base + wrow) * DH;
    #pragma unroll
    for (int r = 0; r < 4; ++r) {
      const float inv = rl[r] > 0.f ? 1.0f / rl[r] : 0.f;
      #pragma unroll
      for (int ct = 0; ct < 4; ++ct)
        op[(lg * 4 + r) * DH + ct * 16 + li] = o[ct][r] * inv;
    }
  }
}

template<int NS>
__global__ __launch_bounds__(256)
void combine(const float* __restrict__ opart,
             const float* __restrict__ mp,
             const float* __restrict__ lp,
             float* __restrict__ outg)
{
  const int gid = blockIdx.x * 256 + threadIdx.x;
  const int rg = gid >> 6;
  const int d  = gid & 63;

  float m[NS], l[NS];
  float M = -1e30f;
  #pragma unroll
  for (int s = 0; s < NS; ++s) {
    m[s] = mp[(size_t)s * ROWS + rg];
    l[s] = lp[(size_t)s * ROWS + rg];
    M = fmaxf(M, m[s]);
  }
  float L = 0.f, acc = 0.f;
  #pragma unroll
  for (int s = 0; s < NS; ++s) {
    float w = __builtin_amdgcn_exp2f(m[s] - M);
    L += w * l[s];
    acc += w * opart[((size_t)s * ROWS + rg) * DH + d];
  }
  outg[(size_t)rg * DH + d] = L > 0.f ? acc / L : 0.f;
}

// ---------------- fallback: self-staging single pass (round-5 proven) -------
__global__ __launch_bounds__(256, 2)
void attn_fallback(const float* __restrict__ qg,
                   const float* __restrict__ kg,
                   const float* __restrict__ vg,
                   const int* __restrict__ qcs_p,
                   float* __restrict__ outg)
{
  __shared__ __align__(16) short Klds[KT * DH];
  __shared__ __align__(16) short Vt[DH * KT];
  __shared__ __align__(16) short Plds[NW][16 * KT];

  const int tid  = threadIdx.x;
  const int wave = tid >> 6;
  const int lane = tid & 63;
  const int lg   = lane >> 4;
  const int li   = lane & 15;

  const int bid = blockIdx.x;
  const int bh  = bid & (NBH - 1);
  const int qt  = bid >> 5;
  const int qcs = *qcs_p;

  const int q_base = qt * QT;
  const int wrow   = wave * 16;

  const float* qp = qg + ((size_t)bh * TQ + q_base + wrow) * DH;
  const float* kp = kg + (size_t)bh * TK * DH;
  const float* vp = vg + (size_t)bh * TK * DH;

  const float qscale = 0.125f * 1.44269504088896f;
  short8 qf[2];
  #pragma unroll
  for (int h = 0; h < 2; ++h) {
    const float* src = qp + li * DH + h * 32 + lg * 8;
    float4 a = *(const float4*)(src);
    float4 b = *(const float4*)(src + 4);
    short8 f;
    f[0] = f2bf(a.x * qscale); f[1] = f2bf(a.y * qscale);
    f[2] = f2bf(a.z * qscale); f[3] = f2bf(a.w * qscale);
    f[4] = f2bf(b.x * qscale); f[5] = f2bf(b.y * qscale);
    f[6] = f2bf(b.z * qscale); f[7] = f2bf(b.w * qscale);
    qf[h] = f;
  }

  f32x4 o[4];
  #pragma unroll
  for (int ct = 0; ct < 4; ++ct) o[ct] = (f32x4){0.f, 0.f, 0.f, 0.f};
  float rm[4], rl[4];
  #pragma unroll
  for (int r = 0; r < 4; ++r) { rm[r] = -1e30f; rl[r] = 0.f; }

  const int lim    = qcs + q_base + QT;
  const int n_keys = lim < TK ? lim : TK;
  const int n_tiles = (n_keys + KT - 1) / KT;

  const int t_key = tid >> 4;
  const int t_d   = (tid & 15) * 4;

  for (int tile = 0; tile < n_tiles; ++tile) {
    const int kt0 = tile * KT;
    #pragma unroll
    for (int it = 0; it < 4; ++it) {
      const int key = t_key + it * 16;
      const size_t goff = (size_t)(kt0 + key) * DH + t_d;
      float4 kv = *(const float4*)(kp + goff);
      short4v ks;
      ks[0] = f2bf(kv.x); ks[1] = f2bf(kv.y); ks[2] = f2bf(kv.z); ks[3] = f2bf(kv.w);
      *(short4v*)(&Klds[(key * DH + t_d) ^ ((key & 7) << 3)]) = ks;

      float4 vv = *(const float4*)(vp + goff);
      Vt[((t_d + 0) * KT + key) ^ ((((t_d + 0) >> 1) & 7) << 3)] = f2bf(vv.x);
      Vt[((t_d + 1) * KT + key) ^ ((((t_d + 1) >> 1) & 7) << 3)] = f2bf(vv.y);
      Vt[((t_d + 2) * KT + key) ^ ((((t_d + 2) >> 1) & 7) << 3)] = f2bf(vv.z);
      Vt[((t_d + 3) * KT + key) ^ ((((t_d + 3) >> 1) & 7) << 3)] = f2bf(vv.w);
    }
    __syncthreads();

    f32x4 sv[4];
    #pragma unroll
    for (int t = 0; t < 4; ++t) {
      f32x4 acc = (f32x4){0.f, 0.f, 0.f, 0.f};
      #pragma unroll
      for (int h = 0; h < 2; ++h) {
        int e = ((t * 16 + li) * DH + h * 32 + lg * 8) ^ ((li & 7) << 3);
        short8 kf = *(const short8*)(&Klds[e]);
        acc = __builtin_amdgcn_mfma_f32_16x16x32_bf16(qf[h], kf, acc, 0, 0, 0);
      }
      sv[t] = acc;
    }

    if (kt0 + KT - 1 > qcs + q_base + wrow) {
      #pragma unroll
      for (int t = 0; t < 4; ++t) {
        const int keyg = kt0 + t * 16 + li;
        #pragma unroll
        for (int r = 0; r < 4; ++r) {
          const int qpos = qcs + q_base + wrow + lg * 4 + r;
          if (keyg > qpos) sv[t][r] = -INFINITY;
        }
      }
    }

    float al[4], mn[4];
    #pragma unroll
    for (int r = 0; r < 4; ++r) {
      float tm = fmaxf(fmaxf(sv[0][r], sv[1][r]), fmaxf(sv[2][r], sv[3][r]));
      #pragma unroll
      for (int off = 1; off < 16; off <<= 1)
        tm = fmaxf(tm, __shfl_xor(tm, off, 64));
      float m2 = fmaxf(rm[r], tm);
      al[r] = __builtin_amdgcn_exp2f(rm[r] - m2);
      mn[r] = m2;
      rm[r] = m2;
    }

    float ps[4] = {0.f, 0.f, 0.f, 0.f};
    #pragma unroll
    for (int t = 0; t < 4; ++t) {
      #pragma unroll
      for (int r = 0; r < 4; ++r) {
        float p = __builtin_amdgcn_exp2f(sv[t][r] - mn[r]);
        ps[r] += p;
        const int row = lg * 4 + r;
        Plds[wave][(row * KT + t * 16 + li) ^ ((row & 7) << 3)] = f2bf(p);
      }
    }

    #pragma unroll
    for (int r = 0; r < 4; ++r) {
      float sum = ps[r];
      #pragma unroll
      for (int off = 1; off < 16; off <<= 1)
        sum += __shfl_xor(sum, off, 64);
      rl[r] = rl[r] * al[r] + sum;
      #pragma unroll
      for (int ct = 0; ct < 4; ++ct) o[ct][r] *= al[r];
    }

    #pragma unroll
    for (int sk = 0; sk < 2; ++sk) {
      int ep = (li * KT + sk * 32 + lg * 8) ^ ((li & 7) << 3);
      short8 pf = *(const short8*)(&Plds[wave][ep]);
      #pragma unroll
      for (int ct = 0; ct < 4; ++ct) {
        int d = ct * 16 + li;
        int ev = (d * KT + sk * 32 + lg * 8) ^ (((d >> 1) & 7) << 3);
        short8 vf = *(const short8*)(&Vt[ev]);
        o[ct] = __builtin_amdgcn_mfma_f32_16x16x32_bf16(pf, vf, o[ct], 0, 0, 0);
      }
    }
    __syncthreads();
  }

  float* op = outg + ((size_t)bh * TQ + q_base + wrow) * DH;
  #pragma unroll
  for (int r = 0; r < 4; ++r) {
    const float inv = rl[r] > 0.f ? 1.0f / rl[r] : 0.f;
    #pragma unroll
    for (int ct = 0; ct < 4; ++ct)
      op[(lg * 4 + r) * DH + ct * 16 + li] = o[ct][r] * inv;
  }
}

extern "C" void kernel_launch(void* const* d_in, const int* in_sizes, int n_in,
                              void* d_out, int out_size, void* d_ws, size_t ws_size,
                              hipStream_t stream) {
  const float* q   = (const float*)d_in[0];
  const float* k   = (const float*)d_in[1];
  const float* v   = (const float*)d_in[2];
  const int*   qcs = (const int*)d_in[3];
  float* out = (float*)d_out;

  constexpr int    NS = 2;
  constexpr size_t IMG_ELEMS = (size_t)NBH * NTILE * TILE_E;        // 16.8M shorts
  constexpr size_t WS_IMG    = 2 * IMG_ELEMS * sizeof(short);       // 67.1 MB
  constexpr size_t O_ELEMS   = (size_t)NS * ROWS * DH;
  constexpr size_t ML_ELEMS  = (size_t)NS * ROWS;
  constexpr size_t WS_FULL   = WS_IMG + (O_ELEMS + 2 * ML_ELEMS) * sizeof(float); // 84.4 MB

  if (ws_size >= WS_FULL) {
    short* Kg2 = (short*)d_ws;
    short* Vg2 = Kg2 + IMG_ELEMS;
    float* opart = (float*)(Vg2 + IMG_ELEMS);
    float* mpart = opart + O_ELEMS;
    float* lpart = mpart + ML_ELEMS;
    prep<<<dim3(NBH * NTILE), dim3(256), 0, stream>>>(k, v, Kg2, Vg2);
    // 1024 blocks == 4 blocks/CU x 256 CUs: fully co-resident, streams aligned
    attn_main<NS, true><<<dim3(NBH * NS * (TQ / QT)), dim3(256), 0, stream>>>(
        q, Kg2, Vg2, qcs, opart, mpart, lpart);
    combine<NS><<<dim3(ROWS * DH / 256), dim3(256), 0, stream>>>(opart, mpart, lpart, out);
  } else if (ws_size >= WS_IMG) {
    short* Kg2 = (short*)d_ws;
    short* Vg2 = Kg2 + IMG_ELEMS;
    prep<<<dim3(NBH * NTILE), dim3(256), 0, stream>>>(k, v, Kg2, Vg2);
    attn_main<1, false><<<dim3(NBH * (TQ / QT)), dim3(256), 0, stream>>>(
        q, Kg2, Vg2, qcs, out, nullptr, nullptr);
  } else {
    attn_fallback<<<dim3(NBH * (TQ / QT)), dim3(256), 0, stream>>>(q, k, v, qcs, out);
  }
}